// Round 1
// baseline (378.064 us; speedup 1.0000x reference)
//
#include <hip/hip_runtime.h>
#include <math.h>

// Problem constants
#define BB  16384
#define DD  64
#define NT_ 128
#define NZ_ 2048
#define NJ_ 2049   // NZ+1

// workspace layout (float offsets)
#define WZ_OFF   0         // [DD][NZ_]   64*2048
#define BIAS_OFF 131072    // [DD]
#define Q_OFF    131136    // [NZ_]
#define CC_OFF   133184    // [NZ_]
#define INV_OFF  135232    // [NZ_]
#define CZT_OFF  137280    // [DD][NZ_]
#define WZT_OFF  268352    // [NZ_][DD]
#define ZT_OFF   399424    // [DD][BB]
// total = 1,448,000 floats ~= 5.8 MB of d_ws

// ---------------------------------------------------------------------------
// Kernel 1: phi_t + W_t = einsum('dij,i->dj').  Splits into Wz [D][NZ] + bias[D].
// W is [D][NT][NJ]; for fixed (d,i) consecutive j are contiguous -> coalesced.
__global__ __launch_bounds__(256) void k_wt(
    const float* __restrict__ t, const float* __restrict__ ct,
    const float* __restrict__ lst, const float* __restrict__ W,
    float* __restrict__ Wz, float* __restrict__ bias)
{
  __shared__ float ph[NT_];
  int tx = threadIdx.x;
  float t0 = t[0];
  if (tx < NT_) {
    float r = fabsf(t0 - ct[tx]) * __expf(-lst[tx]);
    ph[tx] = __expf(-r * r);
  }
  __syncthreads();
  int d = blockIdx.y;
  int j = blockIdx.x * 256 + tx;
  if (j >= NJ_) return;
  const float* Wp = W + (size_t)d * NT_ * NJ_ + j;
  float acc = 0.f;
#pragma unroll 8
  for (int i = 0; i < NT_; ++i) acc += Wp[(size_t)i * NJ_] * ph[i];
  if (j < NZ_) Wz[d * NZ_ + j] = acc;
  else         bias[d] = acc;
}

// ---------------------------------------------------------------------------
// Kernel 2: per-centre q[c] = sum_d Wz[d][c]*cz[c][d], cc[c] = |c|^2, inv[c]
__global__ __launch_bounds__(256) void k_qcc(
    const float* __restrict__ Wz, const float* __restrict__ cz,
    const float* __restrict__ lsz,
    float* __restrict__ q, float* __restrict__ cc, float* __restrict__ inv)
{
  int c = blockIdx.x * 256 + threadIdx.x;
  const float* cr = cz + (size_t)c * DD;
  float qa = 0.f, ca = 0.f;
#pragma unroll 8
  for (int d = 0; d < DD; ++d) {
    float cv = cr[d];
    qa += Wz[(size_t)d * NZ_ + c] * cv;
    ca += cv * cv;
  }
  q[c]  = qa;
  cc[c] = ca;
  inv[c] = __expf(-2.f * lsz[c]);
}

// ---------------------------------------------------------------------------
// Generic 32x32 tiled transpose: dst[c][r] = src[r][c]
__global__ __launch_bounds__(256) void k_tr(
    const float* __restrict__ src, int ldsrc,
    float* __restrict__ dst, int lddst, int R, int C)
{
  __shared__ float tile[32][33];
  int tx = threadIdx.x & 31, ty = threadIdx.x >> 5;  // 32x8
  int c0 = blockIdx.x * 32, r0 = blockIdx.y * 32;
#pragma unroll
  for (int j = ty; j < 32; j += 8) {
    int r = r0 + j, c = c0 + tx;
    if (r < R && c < C) tile[j][tx] = src[(size_t)r * ldsrc + c];
  }
  __syncthreads();
#pragma unroll
  for (int j = ty; j < 32; j += 8) {
    int c = c0 + j, r = r0 + tx;
    if (r < R && c < C) dst[(size_t)c * lddst + r] = tile[tx][j];
  }
}

// ---------------------------------------------------------------------------
// Main fused kernel.
// Per block: BM=32 z-rows; loop c-chunks of KC=64.
// Phase A: dot1 = z.c, dot2 = z.Wz (4x4 micro-tile, float4 LDS reads)
//          -> p = exp(-max(zz+cc-2*dot1,0)*inv); dl += p*inv*(dot2-q)
// Phase B: dz[r][d] += sum_c p[r][c]*Wz[d][c]  (4x4 micro-tile)
#define BM 32
#define KC 64
#define PS_LD 34   // pad: even (float2-aligned), 4-way max bank conflict on writes

__global__ __launch_bounds__(128) void k_fused(
    const float* __restrict__ zT,   // [DD][BB]
    const float* __restrict__ czT,  // [DD][NZ_]
    const float* __restrict__ Wz,   // [DD][NZ_]
    const float* __restrict__ WzT,  // [NZ_][DD]
    const float* __restrict__ bias, // [DD]
    const float* __restrict__ qg, const float* __restrict__ ccg,
    const float* __restrict__ invg,
    float* __restrict__ out)
{
  __shared__ float zs [DD][BM];     // [d][r]   8 KB
  __shared__ float cs [DD][KC];     // [d][c]  16 KB
  __shared__ float wzs[DD][KC];     // [d][c]  16 KB
  __shared__ float wzt[KC][DD];     // [c][d]  16 KB
  __shared__ float ps [KC][PS_LD];  // [c][r]  8.5 KB
  __shared__ float zzs[BM];
  __shared__ float qs[KC], ccs[KC], invs[KC];
  __shared__ float dlred[BM][17];

  int tid  = threadIdx.x;           // 0..127
  int b0   = blockIdx.x * BM;
  int cgrp = tid & 15;              // 16 groups of 4 (c in phase A, d in phase B)
  int rgrp = tid >> 4;              // 8 groups of 4 rows

  // stage z tile: zs[d][r] <- zT[d][b0+r], vectorized
  {
    const float4* z4 = (const float4*)zT;
#pragma unroll
    for (int k = 0; k < 4; ++k) {
      int f = k * 128 + tid;        // 512 float4 = 2048 floats
      int d = f >> 3;               // 8 float4 per 32-float row
      int r4 = f & 7;
      float4 v = z4[((size_t)d * BB + b0) / 4 + r4];
      *(float4*)&zs[d][r4 * 4] = v;
    }
  }
  __syncthreads();
  if (tid < BM) {
    float s = 0.f;
#pragma unroll 8
    for (int d = 0; d < DD; ++d) { float v = zs[d][tid]; s += v * v; }
    zzs[tid] = s;
  }

  float acc[4][4] = {{0.f}};        // dz accumulator [row i][d j]
  float dl[4] = {0.f, 0.f, 0.f, 0.f};

  for (int c0 = 0; c0 < NZ_; c0 += KC) {
    // ---- stage chunk ----
    {
      const float4* a4 = (const float4*)czT;
      const float4* b4 = (const float4*)Wz;
      const float4* w4 = (const float4*)(WzT + (size_t)c0 * DD);
#pragma unroll
      for (int k = 0; k < 8; ++k) {
        int f  = k * 128 + tid;     // 1024 float4 = 4096 floats
        int d  = f >> 4;            // 16 float4 per 64-float row
        int j4 = f & 15;
        size_t src = ((size_t)d * NZ_ + c0) / 4 + j4;
        *(float4*)&cs [d][j4 * 4] = a4[src];
        *(float4*)&wzs[d][j4 * 4] = b4[src];
        ((float4*)wzt)[f] = w4[f];  // contiguous rows c0..c0+63
      }
      if (tid < KC) {
        qs[tid]   = qg [c0 + tid];
        ccs[tid]  = ccg[c0 + tid];
        invs[tid] = invg[c0 + tid];
      }
    }
    __syncthreads();

    // ---- phase A: dots over d ----
    float d1[4][4] = {{0.f}}, d2[4][4] = {{0.f}};
#pragma unroll 4
    for (int d = 0; d < DD; ++d) {
      float4 zv = *(const float4*)&zs [d][rgrp * 4];
      float4 cv = *(const float4*)&cs [d][cgrp * 4];
      float4 wv = *(const float4*)&wzs[d][cgrp * 4];
      float za[4] = {zv.x, zv.y, zv.z, zv.w};
      float ca[4] = {cv.x, cv.y, cv.z, cv.w};
      float wa[4] = {wv.x, wv.y, wv.z, wv.w};
#pragma unroll
      for (int i = 0; i < 4; ++i)
#pragma unroll
        for (int j = 0; j < 4; ++j) {
          d1[i][j] += za[i] * ca[j];
          d2[i][j] += za[i] * wa[j];
        }
    }
    // p, dlogp contribution, write p tile
#pragma unroll
    for (int i = 0; i < 4; ++i) {
      int r = rgrp * 4 + i;
      float zz = zzs[r];
#pragma unroll
      for (int j = 0; j < 4; ++j) {
        int c = cgrp * 4 + j;
        float s = zz + ccs[c] - 2.f * d1[i][j];
        s = fmaxf(s, 0.f);
        float p = __expf(-s * invs[c]);
        ps[c][r] = p;
        dl[i] += p * invs[c] * (d2[i][j] - qs[c]);
      }
    }
    __syncthreads();

    // ---- phase B: dz += p @ WzT ----
#pragma unroll 4
    for (int c = 0; c < KC; ++c) {
      float2 p01 = *(const float2*)&ps[c][rgrp * 4];
      float2 p23 = *(const float2*)&ps[c][rgrp * 4 + 2];
      float4 wv  = *(const float4*)&wzt[c][cgrp * 4];
      float pa[4] = {p01.x, p01.y, p23.x, p23.y};
      float wa[4] = {wv.x, wv.y, wv.z, wv.w};
#pragma unroll
      for (int i = 0; i < 4; ++i)
#pragma unroll
        for (int j = 0; j < 4; ++j)
          acc[i][j] += pa[i] * wa[j];
    }
    __syncthreads();
  }

  // ---- epilogue: dz + bias ----
  {
    float4 bv = *(const float4*)&bias[cgrp * 4];
    float ba[4] = {bv.x, bv.y, bv.z, bv.w};
#pragma unroll
    for (int i = 0; i < 4; ++i) {
      int r = b0 + rgrp * 4 + i;
      float4 o;
      o.x = acc[i][0] + ba[0];
      o.y = acc[i][1] + ba[1];
      o.z = acc[i][2] + ba[2];
      o.w = acc[i][3] + ba[3];
      *(float4*)&out[(size_t)r * DD + cgrp * 4] = o;
    }
  }
  // ---- dlogp: reduce over 16 c-groups ----
#pragma unroll
  for (int i = 0; i < 4; ++i) dlred[rgrp * 4 + i][cgrp] = dl[i];
  __syncthreads();
  if (tid < BM) {
    float s = 0.f;
#pragma unroll
    for (int k = 0; k < 16; ++k) s += dlred[tid][k];
    out[(size_t)BB * DD + b0 + tid] = 2.f * s;
  }
}

// ---------------------------------------------------------------------------
extern "C" void kernel_launch(void* const* d_in, const int* in_sizes, int n_in,
                              void* d_out, int out_size, void* d_ws, size_t ws_size,
                              hipStream_t stream)
{
  const float* t   = (const float*)d_in[0];
  const float* z   = (const float*)d_in[1];
  // d_in[2] = logp_z (unused by the forward outputs)
  const float* cz  = (const float*)d_in[3];
  const float* lsz = (const float*)d_in[4];
  const float* ct  = (const float*)d_in[5];
  const float* lst = (const float*)d_in[6];
  const float* W   = (const float*)d_in[7];
  float* out = (float*)d_out;
  float* ws  = (float*)d_ws;

  // 1) W_t -> Wz + bias
  k_wt<<<dim3(9, 64), 256, 0, stream>>>(t, ct, lst, W, ws + WZ_OFF, ws + BIAS_OFF);
  // 2) WzT = transpose(Wz): src 64x2048 (ld 2048) -> dst 2048x64
  k_tr<<<dim3(64, 2), 256, 0, stream>>>(ws + WZ_OFF, NZ_, ws + WZT_OFF, DD, DD, NZ_);
  // 3) q, cc, inv  (needs Wz)
  k_qcc<<<dim3(8), 256, 0, stream>>>(ws + WZ_OFF, cz, lsz,
                                     ws + Q_OFF, ws + CC_OFF, ws + INV_OFF);
  // 4) czT = transpose(centres_z): src 2048x64 -> dst 64x2048
  k_tr<<<dim3(2, 64), 256, 0, stream>>>(cz, DD, ws + CZT_OFF, NZ_, NZ_, DD);
  // 5) zT = transpose(z): src 16384x64 -> dst 64x16384
  k_tr<<<dim3(2, 512), 256, 0, stream>>>(z, DD, ws + ZT_OFF, BB, BB, DD);
  // 6) fused main
  k_fused<<<dim3(BB / BM), 128, 0, stream>>>(
      ws + ZT_OFF, ws + CZT_OFF, ws + WZ_OFF, ws + WZT_OFF, ws + BIAS_OFF,
      ws + Q_OFF, ws + CC_OFF, ws + INV_OFF, out);
}

// Round 2
// 204.366 us; speedup vs baseline: 1.8499x; 1.8499x over previous
//
#include <hip/hip_runtime.h>
#include <math.h>

typedef unsigned int uint;
typedef unsigned short ushort;
typedef __attribute__((ext_vector_type(8))) short short8;
typedef __attribute__((ext_vector_type(4))) float f32x4;

// Problem constants
#define BB  16384
#define DD  64
#define NT_ 128
#define NZ_ 2048
#define NJ_ 2049   // NZ+1

// workspace layout (float offsets)
#define WZ_OFF   0         // fp32 Wz  [64][2048]
#define BIAS_OFF 131072    // fp32 [64]
#define Q_OFF    131136    // fp32 [2048]
#define CC_OFF   133184    // fp32 [2048]
#define INV_OFF  135232    // fp32 [2048]
#define ZB_OFF   137280    // bf16 z    [16384][64]  (524288 floats)
#define CZB_OFF  661568    // bf16 cz   [2048][64]   (65536 floats)
#define WZTB_OFF 727104    // bf16 WzT  [2048][64]
#define WZB_OFF  792640    // bf16 Wz   [64][2048]
// end 858176 floats = 3.43 MB

__device__ __forceinline__ ushort f2b(float x) {
  uint u = __float_as_uint(x);
  uint r = (u + 0x7FFFu + ((u >> 16) & 1u)) >> 16;
  return (ushort)r;
}
__device__ __forceinline__ float b2f(ushort h) {
  return __uint_as_float(((uint)h) << 16);
}

// ---------------------------------------------------------------------------
// Kernel 1: phi_t + W_t = einsum('dij,i->dj') -> Wz [64][2048] fp32 + bias[64]
__global__ __launch_bounds__(256) void k_wt(
    const float* __restrict__ t, const float* __restrict__ ct,
    const float* __restrict__ lst, const float* __restrict__ W,
    float* __restrict__ Wz, float* __restrict__ bias)
{
  __shared__ float ph[NT_];
  int tx = threadIdx.x;
  float t0 = t[0];
  if (tx < NT_) {
    float r = fabsf(t0 - ct[tx]) * __expf(-lst[tx]);
    ph[tx] = __expf(-r * r);
  }
  __syncthreads();
  int d = blockIdx.y;
  int j = blockIdx.x * 256 + tx;
  if (j >= NJ_) return;
  const float* Wp = W + (size_t)d * NT_ * NJ_ + j;
  float acc = 0.f;
#pragma unroll 8
  for (int i = 0; i < NT_; ++i) acc += Wp[(size_t)i * NJ_] * ph[i];
  if (j < NZ_) Wz[d * NZ_ + j] = acc;
  else         bias[d] = acc;
}

// ---------------------------------------------------------------------------
// Kernel 2: per-centre q/cc/inv (fp32) + bf16 copies cz[c][d], WzT[c][d], Wz[d][c]
__global__ __launch_bounds__(256) void k_prep_c(
    const float* __restrict__ cz, const float* __restrict__ lsz,
    const float* __restrict__ Wz,
    float* __restrict__ q, float* __restrict__ cc, float* __restrict__ inv,
    ushort* __restrict__ czb, ushort* __restrict__ wztb, ushort* __restrict__ wzb)
{
  int c = blockIdx.x * 256 + threadIdx.x;   // 0..2047
  float qa = 0.f, ca = 0.f;
#pragma unroll 8
  for (int d = 0; d < DD; ++d) {
    float wv = Wz[(size_t)d * NZ_ + c];
    float cv = cz[(size_t)c * DD + d];
    qa += wv * cv;
    ca += cv * cv;
    czb [(size_t)c * DD + d]  = f2b(cv);
    wztb[(size_t)c * DD + d]  = f2b(wv);
    wzb [(size_t)d * NZ_ + c] = f2b(wv);
  }
  q[c]  = qa;
  cc[c] = ca;
  inv[c] = __expf(-2.f * lsz[c]);
}

// ---------------------------------------------------------------------------
// Kernel 3: z -> bf16 (row-major, unchanged layout)
__global__ __launch_bounds__(256) void k_zb(
    const float* __restrict__ z, ushort* __restrict__ zb)
{
  int f = blockIdx.x * 256 + threadIdx.x;   // 0..131071, 8 elems each
  const float4* z4 = (const float4*)z;
  float4 v0 = z4[f * 2], v1 = z4[f * 2 + 1];
  short8 o;
  o[0] = (short)f2b(v0.x); o[1] = (short)f2b(v0.y);
  o[2] = (short)f2b(v0.z); o[3] = (short)f2b(v0.w);
  o[4] = (short)f2b(v1.x); o[5] = (short)f2b(v1.y);
  o[6] = (short)f2b(v1.z); o[7] = (short)f2b(v1.w);
  *(short8*)(zb + (size_t)f * 8) = o;
}

// ---------------------------------------------------------------------------
// Main fused MFMA kernel.
// Block: 256 thr = 4 waves; BM=64 rows (16/wave); loop KC=32 centres.
// GEMM1: S=[dot1|dot2] = z @ [czT | Wz]  (A=z[m][k], B stored [n][k])
// elementwise: phi=exp(-max(zz+cc-2*dot1,0)*inv), dl+=phi*inv*(dot2-q)
// GEMM2: dz += phi @ WzT  (A=phi[m][k=c], B=[d][c])
#define BM 64
#define KC 32

__global__ __launch_bounds__(256) void k_mfma(
    const ushort* __restrict__ zb,   // [BB][64] bf16
    const ushort* __restrict__ czb,  // [NZ][64] bf16
    const ushort* __restrict__ wztb, // [NZ][64] bf16
    const ushort* __restrict__ wzb,  // [64][NZ] bf16
    const float* __restrict__ qg, const float* __restrict__ ccg,
    const float* __restrict__ invg, const float* __restrict__ bias,
    float* __restrict__ out)
{
  __shared__ ushort zt [64][72];     // z tile   [r][d], stride 72 (144B, bank-spread)
  __shared__ ushort csb[32][72];     // cz chunk [c][d]
  __shared__ ushort wsb[32][72];     // WzT chunk[c][d]
  __shared__ ushort wbb[64][48];     // Wz chunk [d][c_local], stride 48 (96B)
  __shared__ ushort phs[4][16][48];  // phi per wave [r][c_local]
  __shared__ float zzs[64];
  __shared__ float qs[KC], ccs[KC], invs[KC];

  int tid  = threadIdx.x;
  int wave = tid >> 6, lane = tid & 63;
  int lrow = lane & 15, quad = lane >> 4;
  int b0 = blockIdx.x * BM;

  // stage z tile (64 rows x 128 B)
#pragma unroll
  for (int k = 0; k < 2; ++k) {
    int f = k * 256 + tid;
    int r = f >> 3, s = f & 7;
    *(short8*)&zt[r][s * 8] = *(const short8*)(zb + (size_t)(b0 + r) * DD + s * 8);
  }
  __syncthreads();
  if (tid < 64) {
    float a = 0.f;
#pragma unroll 8
    for (int s = 0; s < DD; ++s) { float v = b2f(zt[tid][s]); a += v * v; }
    zzs[tid] = a;
  }

  f32x4 acc[4];
#pragma unroll
  for (int nt = 0; nt < 4; ++nt) acc[nt] = (f32x4){0.f, 0.f, 0.f, 0.f};
  float dl[4] = {0.f, 0.f, 0.f, 0.f};

  for (int c0 = 0; c0 < NZ_; c0 += KC) {
    __syncthreads();   // protect staging buffers from previous iter's readers
    {
      int r = tid >> 3, s = tid & 7;
      *(short8*)&csb[r][s * 8] = *(const short8*)(czb  + (size_t)(c0 + r) * DD + s * 8);
      *(short8*)&wsb[r][s * 8] = *(const short8*)(wztb + (size_t)(c0 + r) * DD + s * 8);
      int d = tid >> 2, s2 = tid & 3;
      *(short8*)&wbb[d][s2 * 8] = *(const short8*)(wzb + (size_t)d * NZ_ + c0 + s2 * 8);
      if (tid < KC) {
        qs[tid]   = qg [c0 + tid];
        ccs[tid]  = ccg[c0 + tid];
        invs[tid] = invg[c0 + tid];
      }
    }
    __syncthreads();

    // ---- GEMM1 + elementwise ----
    short8 a0 = *(const short8*)&zt[wave * 16 + lrow][quad * 8];
    short8 a1 = *(const short8*)&zt[wave * 16 + lrow][32 + quad * 8];
    f32x4 z4 = (f32x4){0.f, 0.f, 0.f, 0.f};
#pragma unroll
    for (int nt = 0; nt < 2; ++nt) {
      short8 bc0 = *(const short8*)&csb[nt * 16 + lrow][quad * 8];
      short8 bc1 = *(const short8*)&csb[nt * 16 + lrow][32 + quad * 8];
      short8 bw0 = *(const short8*)&wsb[nt * 16 + lrow][quad * 8];
      short8 bw1 = *(const short8*)&wsb[nt * 16 + lrow][32 + quad * 8];
      f32x4 d1 = __builtin_amdgcn_mfma_f32_16x16x32_bf16(a0, bc0, z4, 0, 0, 0);
      d1       = __builtin_amdgcn_mfma_f32_16x16x32_bf16(a1, bc1, d1, 0, 0, 0);
      f32x4 d2 = __builtin_amdgcn_mfma_f32_16x16x32_bf16(a0, bw0, z4, 0, 0, 0);
      d2       = __builtin_amdgcn_mfma_f32_16x16x32_bf16(a1, bw1, d2, 0, 0, 0);
      int cl = nt * 16 + lrow;
      float ccv = ccs[cl], iv = invs[cl], qv = qs[cl];
#pragma unroll
      for (int i = 0; i < 4; ++i) {
        float s = zzs[wave * 16 + quad * 4 + i] + ccv - 2.f * d1[i];
        s = fmaxf(s, 0.f);
        float p = __expf(-s * iv);
        dl[i] += p * iv * (d2[i] - qv);
        phs[wave][quad * 4 + i][cl] = f2b(p);
      }
    }

    // ---- GEMM2: dz += phi @ WzT (wave-private phi; compiler orders LDS deps) ----
    short8 ap = *(const short8*)&phs[wave][lrow][quad * 8];
#pragma unroll
    for (int nt = 0; nt < 4; ++nt) {
      short8 bb = *(const short8*)&wbb[nt * 16 + lrow][quad * 8];
      acc[nt] = __builtin_amdgcn_mfma_f32_16x16x32_bf16(ap, bb, acc[nt], 0, 0, 0);
    }
  }

  // ---- epilogue: dz + bias ----
#pragma unroll
  for (int nt = 0; nt < 4; ++nt) {
    float bv = bias[nt * 16 + lrow];
#pragma unroll
    for (int i = 0; i < 4; ++i) {
      int row = b0 + wave * 16 + quad * 4 + i;
      out[(size_t)row * DD + nt * 16 + lrow] = acc[nt][i] + bv;
    }
  }
  // ---- dlogp: reduce per-row partials across the 16 lanes of each quad ----
#pragma unroll
  for (int i = 0; i < 4; ++i) {
    float v = dl[i];
    v += __shfl_xor(v, 1, 64);
    v += __shfl_xor(v, 2, 64);
    v += __shfl_xor(v, 4, 64);
    v += __shfl_xor(v, 8, 64);
    if (lrow == 0)
      out[(size_t)BB * DD + b0 + wave * 16 + quad * 4 + i] = 2.f * v;
  }
}

// ---------------------------------------------------------------------------
extern "C" void kernel_launch(void* const* d_in, const int* in_sizes, int n_in,
                              void* d_out, int out_size, void* d_ws, size_t ws_size,
                              hipStream_t stream)
{
  const float* t   = (const float*)d_in[0];
  const float* z   = (const float*)d_in[1];
  // d_in[2] = logp_z (unused)
  const float* cz  = (const float*)d_in[3];
  const float* lsz = (const float*)d_in[4];
  const float* ct  = (const float*)d_in[5];
  const float* lst = (const float*)d_in[6];
  const float* W   = (const float*)d_in[7];
  float* out = (float*)d_out;
  float* ws  = (float*)d_ws;

  float*  Wzp  = ws + WZ_OFF;
  float*  bias = ws + BIAS_OFF;
  float*  q    = ws + Q_OFF;
  float*  cc   = ws + CC_OFF;
  float*  inv  = ws + INV_OFF;
  ushort* zbp  = (ushort*)(ws + ZB_OFF);
  ushort* czb  = (ushort*)(ws + CZB_OFF);
  ushort* wztb = (ushort*)(ws + WZTB_OFF);
  ushort* wzb  = (ushort*)(ws + WZB_OFF);

  k_wt<<<dim3(9, 64), 256, 0, stream>>>(t, ct, lst, W, Wzp, bias);
  k_prep_c<<<dim3(8), 256, 0, stream>>>(cz, lsz, Wzp, q, cc, inv, czb, wztb, wzb);
  k_zb<<<dim3(512), 256, 0, stream>>>(z, zbp);
  k_mfma<<<dim3(BB / BM), 256, 0, stream>>>(zbp, czb, wztb, wzb, q, cc, inv, bias, out);
}

// Round 3
// 165.028 us; speedup vs baseline: 2.2909x; 1.2384x over previous
//
#include <hip/hip_runtime.h>
#include <math.h>

typedef unsigned int uint;
typedef unsigned short ushort;
typedef __attribute__((ext_vector_type(8))) short short8;
typedef __attribute__((ext_vector_type(4))) float f32x4;

// Problem constants
#define BB  16384
#define DD  64
#define NT_ 128
#define NZ_ 2048
#define NJ_ 2049   // NZ+1

// workspace layout (float offsets)
#define BIAS_OFF 0         // fp32 [64]
#define Q_OFF    64        // fp32 [2048]
#define CC_OFF   2112      // fp32 [2048]
#define INV_OFF  4160      // fp32 [2048]
#define ZB_OFF   6208      // bf16 z    [BB][64]  (524288 float slots)
#define CZB_OFF  530496    // bf16 cz   [NZ][64]
#define WZTB_OFF 596032    // bf16 WzT  [NZ][64]
#define WZB_OFF  661568    // bf16 Wz   [64][NZ]
// end 727104 floats = 2.9 MB

__device__ __forceinline__ ushort f2b(float x) {
  uint u = __float_as_uint(x);
  uint r = (u + 0x7FFFu + ((u >> 16) & 1u)) >> 16;
  return (ushort)r;
}
__device__ __forceinline__ float b2f(ushort h) {
  return __uint_as_float(((uint)h) << 16);
}

// ---------------------------------------------------------------------------
// Kernel 1: phi_t + W_t = einsum('dij,i->dj') -> bf16 Wz [64][2048] + fp32 bias
__global__ __launch_bounds__(256) void k_wt(
    const float* __restrict__ t, const float* __restrict__ ct,
    const float* __restrict__ lst, const float* __restrict__ W,
    ushort* __restrict__ wzb, float* __restrict__ bias)
{
  __shared__ float ph[NT_];
  int tx = threadIdx.x;
  float t0 = t[0];
  if (tx < NT_) {
    float r = fabsf(t0 - ct[tx]) * __expf(-lst[tx]);
    ph[tx] = __expf(-r * r);
  }
  __syncthreads();
  int d = blockIdx.y;
  int j = blockIdx.x * 256 + tx;
  if (j >= NJ_) return;
  const float* Wp = W + (size_t)d * NT_ * NJ_ + j;
  float acc = 0.f;
#pragma unroll 16
  for (int i = 0; i < NT_; ++i) acc += Wp[(size_t)i * NJ_] * ph[i];
  if (j < NZ_) wzb[d * NZ_ + j] = f2b(acc);
  else         bias[d] = acc;
}

// ---------------------------------------------------------------------------
// Kernel 2: per-centre q/cc/inv + bf16 czb[c][d], wztb[c][d].
// 32 blocks x 256 thr; block handles 64 centres; Wz tile staged in LDS.
__global__ __launch_bounds__(256) void k_prep(
    const float* __restrict__ cz, const float* __restrict__ lsz,
    const ushort* __restrict__ wzb,
    float* __restrict__ q, float* __restrict__ cc, float* __restrict__ inv,
    ushort* __restrict__ czb, ushort* __restrict__ wztb)
{
  __shared__ ushort wt[64][72];   // [d][c_local]
  int tid = threadIdx.x;
  int cb0 = blockIdx.x * 64;
  // stage wzb tile: 64 d-rows x 64 c (coalesced short8 loads)
#pragma unroll
  for (int k = 0; k < 2; ++k) {
    int f = k * 256 + tid;        // 512 short8
    int d = f >> 3, s = f & 7;
    *(short8*)&wt[d][s * 8] = *(const short8*)(wzb + (size_t)d * NZ_ + cb0 + s * 8);
  }
  __syncthreads();
  int c_l = tid >> 2, part = tid & 3;   // 4 threads per centre
  int c = cb0 + c_l;
  float qa = 0.f, ca = 0.f;
  ushort czl[16];
  const float4* cz4 = (const float4*)(cz + (size_t)c * DD + part * 16);
#pragma unroll
  for (int x = 0; x < 4; ++x) {
    float4 v = cz4[x];
    float va[4] = {v.x, v.y, v.z, v.w};
#pragma unroll
    for (int k = 0; k < 4; ++k) {
      int d = part * 16 + x * 4 + k;
      ca += va[k] * va[k];
      qa += b2f(wt[d][c_l]) * va[k];
      czl[x * 4 + k] = f2b(va[k]);
    }
  }
  // write czb (2 short8)
  {
    short8 o0, o1;
#pragma unroll
    for (int k = 0; k < 8; ++k) { o0[k] = (short)czl[k]; o1[k] = (short)czl[8 + k]; }
    *(short8*)(czb + (size_t)c * DD + part * 16)     = o0;
    *(short8*)(czb + (size_t)c * DD + part * 16 + 8) = o1;
  }
  // write wztb[c][d-range] from LDS column
  {
    short8 o0, o1;
#pragma unroll
    for (int k = 0; k < 8; ++k) {
      o0[k] = (short)wt[part * 16 + k][c_l];
      o1[k] = (short)wt[part * 16 + 8 + k][c_l];
    }
    *(short8*)(wztb + (size_t)c * DD + part * 16)     = o0;
    *(short8*)(wztb + (size_t)c * DD + part * 16 + 8) = o1;
  }
  // reduce q, cc across 4 parts
  qa += __shfl_xor(qa, 1); qa += __shfl_xor(qa, 2);
  ca += __shfl_xor(ca, 1); ca += __shfl_xor(ca, 2);
  if (part == 0) {
    q[c]  = qa;
    cc[c] = ca;
    inv[c] = __expf(-2.f * lsz[c]);
  }
}

// ---------------------------------------------------------------------------
// Kernel 3: z -> bf16
__global__ __launch_bounds__(256) void k_zb(
    const float* __restrict__ z, ushort* __restrict__ zb)
{
  int f = blockIdx.x * 256 + threadIdx.x;
  const float4* z4 = (const float4*)z;
  float4 v0 = z4[f * 2], v1 = z4[f * 2 + 1];
  short8 o;
  o[0] = (short)f2b(v0.x); o[1] = (short)f2b(v0.y);
  o[2] = (short)f2b(v0.z); o[3] = (short)f2b(v0.w);
  o[4] = (short)f2b(v1.x); o[5] = (short)f2b(v1.y);
  o[6] = (short)f2b(v1.z); o[7] = (short)f2b(v1.w);
  *(short8*)(zb + (size_t)f * 8) = o;
}

// ---------------------------------------------------------------------------
// Main fused MFMA kernel — barrier-free K-loop.
// Block: 512 thr = 8 waves = 4-way c-split (ws) x 2 row-halves (h).
// Each wave: 2 M-tiles (32 rows), B-fragments loaded direct from global.
#define KC 32

__global__ __launch_bounds__(512) void k_fused(
    const ushort* __restrict__ zb,   // [BB][64] bf16
    const ushort* __restrict__ czb,  // [NZ][64] bf16
    const ushort* __restrict__ wztb, // [NZ][64] bf16
    const ushort* __restrict__ wzb,  // [64][NZ] bf16
    const float* __restrict__ qg, const float* __restrict__ ccg,
    const float* __restrict__ invg, const float* __restrict__ bias,
    float* __restrict__ out)
{
  __shared__ float qs[NZ_], ccs[NZ_], invs[NZ_];   // 24 KB
  __shared__ ushort phs[8][2][16][40];             // wave-private phi, 20 KB
  __shared__ float eps[64][68];                    // dz combine, 17 KB
  __shared__ float dlr[4][64];                     // dl partials, 1 KB

  int tid  = threadIdx.x;
  int wv   = tid >> 6, lane = tid & 63;
  int lrow = lane & 15, quad = lane >> 4;
  int ws = wv >> 1;          // c-split group 0..3
  int h  = wv & 1;           // row half 0..1
  int b0 = blockIdx.x * 64;

  // stage per-centre scalars (whole NZ range), one barrier
#pragma unroll
  for (int k = 0; k < 4; ++k) {
    int idx = k * 512 + tid;
    qs[idx] = qg[idx]; ccs[idx] = ccg[idx]; invs[idx] = invg[idx];
  }

  // z A-fragments direct from global (2 M-tiles x 2 k-halves)
  short8 a[2][2];
#pragma unroll
  for (int mt = 0; mt < 2; ++mt) {
    const ushort* zr = zb + (size_t)(b0 + h * 32 + mt * 16 + lrow) * DD;
    a[mt][0] = *(const short8*)(zr + quad * 8);
    a[mt][1] = *(const short8*)(zr + 32 + quad * 8);
  }
  // zz per row from fragments + cross-lane reduce
  float zzr[2][4];
#pragma unroll
  for (int mt = 0; mt < 2; ++mt) {
    float p = 0.f;
#pragma unroll
    for (int k = 0; k < 8; ++k) {
      float v0 = b2f((ushort)a[mt][0][k]), v1 = b2f((ushort)a[mt][1][k]);
      p += v0 * v0 + v1 * v1;
    }
    p += __shfl_xor(p, 16);
    p += __shfl_xor(p, 32);          // lane(lrow,*) now holds zz[row base+lrow]
#pragma unroll
    for (int i = 0; i < 4; ++i) zzr[mt][i] = __shfl(p, quad * 4 + i);
  }
  __syncthreads();   // scalars ready

  f32x4 acc[2][4];
#pragma unroll
  for (int mt = 0; mt < 2; ++mt)
#pragma unroll
    for (int nt = 0; nt < 4; ++nt) acc[mt][nt] = (f32x4){0.f, 0.f, 0.f, 0.f};
  float dl[2][4] = {{0.f}};

  const f32x4 zero = (f32x4){0.f, 0.f, 0.f, 0.f};
  int cbase = ws * 512;
  for (int cc0 = 0; cc0 < 512; cc0 += KC) {
    int c0 = cbase + cc0;
    // ---- GEMM1 + elementwise (2 n-tiles of 16 centres) ----
#pragma unroll
    for (int nt = 0; nt < 2; ++nt) {
      const ushort* cr = czb  + (size_t)(c0 + nt * 16 + lrow) * DD;
      const ushort* wr = wztb + (size_t)(c0 + nt * 16 + lrow) * DD;
      short8 bc0 = *(const short8*)(cr + quad * 8);
      short8 bc1 = *(const short8*)(cr + 32 + quad * 8);
      short8 bw0 = *(const short8*)(wr + quad * 8);
      short8 bw1 = *(const short8*)(wr + 32 + quad * 8);
      int cl = nt * 16 + lrow, cg = c0 + cl;
      float ccv = ccs[cg], iv = invs[cg], qv = qs[cg];
#pragma unroll
      for (int mt = 0; mt < 2; ++mt) {
        f32x4 d1 = __builtin_amdgcn_mfma_f32_16x16x32_bf16(a[mt][0], bc0, zero, 0, 0, 0);
        d1       = __builtin_amdgcn_mfma_f32_16x16x32_bf16(a[mt][1], bc1, d1,   0, 0, 0);
        f32x4 d2 = __builtin_amdgcn_mfma_f32_16x16x32_bf16(a[mt][0], bw0, zero, 0, 0, 0);
        d2       = __builtin_amdgcn_mfma_f32_16x16x32_bf16(a[mt][1], bw1, d2,   0, 0, 0);
#pragma unroll
        for (int i = 0; i < 4; ++i) {
          float s = zzr[mt][i] + ccv - 2.f * d1[i];
          s = fmaxf(s, 0.f);
          float p = __expf(-s * iv);
          dl[mt][i] += p * iv * (d2[i] - qv);
          phs[wv][mt][quad * 4 + i][cl] = f2b(p);
        }
      }
    }
    // ---- GEMM2: dz += phi @ Wz (B direct from global, reused across M-tiles) ----
    short8 ap0 = *(const short8*)&phs[wv][0][lrow][quad * 8];
    short8 ap1 = *(const short8*)&phs[wv][1][lrow][quad * 8];
#pragma unroll
    for (int nt = 0; nt < 4; ++nt) {
      short8 bb = *(const short8*)(wzb + (size_t)(nt * 16 + lrow) * NZ_ + c0 + quad * 8);
      acc[0][nt] = __builtin_amdgcn_mfma_f32_16x16x32_bf16(ap0, bb, acc[0][nt], 0, 0, 0);
      acc[1][nt] = __builtin_amdgcn_mfma_f32_16x16x32_bf16(ap1, bb, acc[1][nt], 0, 0, 0);
    }
  }

  // ---- dl partials: reduce across lrow lanes, write per (ws,row) ----
#pragma unroll
  for (int mt = 0; mt < 2; ++mt)
#pragma unroll
    for (int i = 0; i < 4; ++i) {
      float v = dl[mt][i];
      v += __shfl_xor(v, 1);
      v += __shfl_xor(v, 2);
      v += __shfl_xor(v, 4);
      v += __shfl_xor(v, 8);
      if (lrow == 0) dlr[ws][h * 32 + mt * 16 + quad * 4 + i] = v;
    }

  // ---- dz combine across the 4 c-split groups (sequential RMW passes) ----
  for (int s = 0; s < 4; ++s) {
    __syncthreads();
    if (ws == s) {
#pragma unroll
      for (int mt = 0; mt < 2; ++mt)
#pragma unroll
        for (int nt = 0; nt < 4; ++nt)
#pragma unroll
          for (int i = 0; i < 4; ++i) {
            int r = h * 32 + mt * 16 + quad * 4 + i;
            int d = nt * 16 + lrow;
            if (s == 0) eps[r][d] = acc[mt][nt][i];
            else        eps[r][d] += acc[mt][nt][i];
          }
    }
  }
  __syncthreads();

  // ---- outputs ----
  {
    int r = tid >> 3, d0 = (tid & 7) * 8;   // 512 thr x 8 floats = 64x64
    float4 e0 = *(const float4*)&eps[r][d0];
    float4 e1 = *(const float4*)&eps[r][d0 + 4];
    float4 bv0 = *(const float4*)&bias[d0];
    float4 bv1 = *(const float4*)&bias[d0 + 4];
    float4 o0, o1;
    o0.x = e0.x + bv0.x; o0.y = e0.y + bv0.y; o0.z = e0.z + bv0.z; o0.w = e0.w + bv0.w;
    o1.x = e1.x + bv1.x; o1.y = e1.y + bv1.y; o1.z = e1.z + bv1.z; o1.w = e1.w + bv1.w;
    *(float4*)&out[(size_t)(b0 + r) * DD + d0]     = o0;
    *(float4*)&out[(size_t)(b0 + r) * DD + d0 + 4] = o1;
  }
  if (tid < 64) {
    float s = dlr[0][tid] + dlr[1][tid] + dlr[2][tid] + dlr[3][tid];
    out[(size_t)BB * DD + b0 + tid] = 2.f * s;
  }
}

// ---------------------------------------------------------------------------
extern "C" void kernel_launch(void* const* d_in, const int* in_sizes, int n_in,
                              void* d_out, int out_size, void* d_ws, size_t ws_size,
                              hipStream_t stream)
{
  const float* t   = (const float*)d_in[0];
  const float* z   = (const float*)d_in[1];
  // d_in[2] = logp_z (unused)
  const float* cz  = (const float*)d_in[3];
  const float* lsz = (const float*)d_in[4];
  const float* ct  = (const float*)d_in[5];
  const float* lst = (const float*)d_in[6];
  const float* W   = (const float*)d_in[7];
  float* out = (float*)d_out;
  float* ws  = (float*)d_ws;

  float*  bias = ws + BIAS_OFF;
  float*  q    = ws + Q_OFF;
  float*  cc   = ws + CC_OFF;
  float*  inv  = ws + INV_OFF;
  ushort* zbp  = (ushort*)(ws + ZB_OFF);
  ushort* czb  = (ushort*)(ws + CZB_OFF);
  ushort* wztb = (ushort*)(ws + WZTB_OFF);
  ushort* wzb  = (ushort*)(ws + WZB_OFF);

  k_wt<<<dim3(9, 64), 256, 0, stream>>>(t, ct, lst, W, wzb, bias);
  k_prep<<<dim3(32), 256, 0, stream>>>(cz, lsz, wzb, q, cc, inv, czb, wztb);
  k_zb<<<dim3(512), 256, 0, stream>>>(z, zbp);
  k_fused<<<dim3(BB / 64), 512, 0, stream>>>(zbp, czb, wztb, wzb, q, cc, inv, bias, out);
}